// Round 12
// baseline (20.610 us; speedup 1.0000x reference)
//
#include <hip/hip_runtime.h>
#include <math.h>

#define DIAG_MIN 0.316f
#define DIAG_MAX 3.16f

typedef short bf16x8 __attribute__((ext_vector_type(8)));
typedef float f32x4  __attribute__((ext_vector_type(4)));

// rc (compact lower-tri index) -> W2 row r = i*16+k  (runtime staging use)
__device__ const unsigned char R_OF_RC[136] = {
    0,
    16,17,
    32,33,34,
    48,49,50,51,
    64,65,66,67,68,
    80,81,82,83,84,85,
    96,97,98,99,100,101,102,
    112,113,114,115,116,117,118,119,
    128,129,130,131,132,133,134,135,136,
    144,145,146,147,148,149,150,151,152,153,
    160,161,162,163,164,165,166,167,168,169,170,
    176,177,178,179,180,181,182,183,184,185,186,187,
    192,193,194,195,196,197,198,199,200,201,202,203,204,
    208,209,210,211,212,213,214,215,216,217,218,219,220,221,
    224,225,226,227,228,229,230,231,232,233,234,235,236,237,238,
    240,241,242,243,244,245,246,247,248,249,250,251,252,253,254,255
};
// rc -> k (column of L); compile-time folded only
constexpr unsigned char K_C[144] = {
    0,
    0,1,
    0,1,2,
    0,1,2,3,
    0,1,2,3,4,
    0,1,2,3,4,5,
    0,1,2,3,4,5,6,
    0,1,2,3,4,5,6,7,
    0,1,2,3,4,5,6,7,8,
    0,1,2,3,4,5,6,7,8,9,
    0,1,2,3,4,5,6,7,8,9,10,
    0,1,2,3,4,5,6,7,8,9,10,11,
    0,1,2,3,4,5,6,7,8,9,10,11,12,
    0,1,2,3,4,5,6,7,8,9,10,11,12,13,
    0,1,2,3,4,5,6,7,8,9,10,11,12,13,14,
    0,1,2,3,4,5,6,7,8,9,10,11,12,13,14,15,
    0,0,0,0,0,0,0,0
};
// rc -> i (row of L); compile-time folded only
constexpr unsigned char I_C[144] = {
    0,
    1,1,
    2,2,2,
    3,3,3,3,
    4,4,4,4,4,
    5,5,5,5,5,5,
    6,6,6,6,6,6,6,
    7,7,7,7,7,7,7,7,
    8,8,8,8,8,8,8,8,8,
    9,9,9,9,9,9,9,9,9,9,
    10,10,10,10,10,10,10,10,10,10,10,
    11,11,11,11,11,11,11,11,11,11,11,11,
    12,12,12,12,12,12,12,12,12,12,12,12,12,
    13,13,13,13,13,13,13,13,13,13,13,13,13,13,
    14,14,14,14,14,14,14,14,14,14,14,14,14,14,14,
    15,15,15,15,15,15,15,15,15,15,15,15,15,15,15,15,
    0,0,0,0,0,0,0,0
};

__device__ __forceinline__ short f2bf(float f) {  // RNE
    unsigned u = __float_as_uint(f);
    return (short)((u + 0x7FFFu + ((u >> 16) & 1u)) >> 16);
}
__device__ __forceinline__ unsigned pk(float a, float b) {
    return (unsigned)(unsigned short)f2bf(a) | ((unsigned)(unsigned short)f2bf(b) << 16);
}
__device__ __forceinline__ float silu(float x) {
    return x * __frcp_rn(1.0f + __expf(-x));
}

// Register-only epilogue for kgrp G: lane holds P[rc=16t+4G+q][m=own arow]
// in acc[t][q] (b2 already added via MFMA C). Diag slots (K==I): +1 identity,
// softplus, clamp. Scatter z = P*dx[i(rc)] into y[k(rc)] — after full unroll
// every index is a compile-time constant -> y stays in registers.
template<int G>
__device__ __forceinline__ void epi(const f32x4 (&acc)[9],
                                    const float (&dxv)[16], float (&y)[16]) {
    #pragma unroll
    for (int t = 0; t < 9; ++t) {
        #pragma unroll
        for (int q = 0; q < 4; ++q) {
            const int rc = 16 * t + 4 * G + q;
            if (rc <= 135) {                    // constant-folds per (t,q)
                const int K = K_C[rc];
                const int I = I_C[rc];
                float p = acc[t][q];
                if (K == I) {                   // diagonal (constant-folds)
                    float sp = __logf(1.0f + __expf(p + 1.0f));
                    p = fminf(fmaxf(sp, DIAG_MIN), DIAG_MAX);
                }
                y[K] = fmaf(p, dxv[I], y[K]);
            }
        }
    }
}

// Block = 4 waves = 64 outputs; grid 2048. ONE barrier, then fully
// independent waves: swapped layer-2 MFMA (A=W2 frag, B=h frag) gives each
// lane P[rc][its OWN m]; dx/h/P/y all register-resident; y[16] summed
// across the 4 kgrp-lanes by a 32-shfl butterfly. No Pl, no phase B.
// LDS: w2t 9216 B + b2c 576 B = 9.8 KB.
__global__ __launch_bounds__(256, 4) void rm_kernel(
    const float* __restrict__ x1, const float* __restrict__ x2,
    const float* __restrict__ W1, const float* __restrict__ b1,
    const float* __restrict__ W2, const float* __restrict__ b2,
    float* __restrict__ out)
{
    __shared__ __align__(16) short w2t[4608];   // 9216 B, pi-permuted cols
    __shared__ __align__(16) float b2c[144];    //  576 B, compact b2

    const int tid  = threadIdx.x;
    const int lane = tid & 63;
    const int wid  = tid >> 6;
    const int blk  = blockIdx.x;
    const int mc   = blk & 3;
    const int bn   = blk >> 2;
    const int b    = bn >> 8;

    const int arow = lane & 15;
    const int kgrp = lane >> 4;
    const int m    = mc * 64 + wid * 16 + arow;

    // ---- stage W2 -> w2t (pi-permuted cols, verified R9) + b2 -> b2c ----
    #pragma unroll
    for (int it = 0; it < 2; ++it) {
        const int rc = it * 128 + (tid >> 1);
        if (rc < 144) {
            const int rcs = rc > 135 ? 135 : rc;
            const int r = R_OF_RC[rcs];
            const int hf = tid & 1;
            const float4* s4 = (const float4*)(W2 + r * 32 + hf * 16);
            float4 v0 = s4[0], v1 = s4[1], v2 = s4[2], v3 = s4[3];
            short* base = w2t + (((rc >> 4) * 4) * 16 + (rc & 15)) * 8 + 4 * hf;
            uint2 w0 = {pk(v0.x, v0.y), pk(v0.z, v0.w)};
            uint2 w1 = {pk(v1.x, v1.y), pk(v1.z, v1.w)};
            uint2 w2v = {pk(v2.x, v2.y), pk(v2.z, v2.w)};
            uint2 w3 = {pk(v3.x, v3.y), pk(v3.z, v3.w)};
            *(uint2*)(base)          = w0;
            *(uint2*)(base + 16 * 8) = w1;
            *(uint2*)(base + 32 * 8) = w2v;
            *(uint2*)(base + 48 * 8) = w3;
        }
    }
    if (tid < 144) b2c[tid] = b2[R_OF_RC[tid > 135 ? 135 : tid]];

    // ---- mid + dx (registers only) ----
    const float4* a4 = (const float4*)(x1 + bn * 16);
    const float4* c4 = (const float4*)(x2 + (b * 256 + m) * 16);
    float mid[16], dxv[16];
    #pragma unroll
    for (int q = 0; q < 4; ++q) {
        float4 va = a4[q], vb = c4[q];
        mid[4*q+0] = (va.x + vb.x) * 0.5f;  dxv[4*q+0] = vb.x - va.x;
        mid[4*q+1] = (va.y + vb.y) * 0.5f;  dxv[4*q+1] = vb.y - va.y;
        mid[4*q+2] = (va.z + vb.z) * 0.5f;  dxv[4*q+2] = vb.z - va.z;
        mid[4*q+3] = (va.w + vb.w) * 0.5f;  dxv[4*q+3] = vb.w - va.w;
    }

    // ---- layer 1: H^T = W1 @ mid^T, 2 MFMAs (verified R9) ----
    bf16x8 Bm;   // B[i=8kgrp+jo][m=arow] = mid[8kgrp+jo] (0 for i>=16)
    #pragma unroll
    for (int jo = 0; jo < 8; ++jo) {
        float v = kgrp == 0 ? mid[jo] : (kgrp == 1 ? mid[8 + jo] : 0.0f);
        Bm[jo] = f2bf(v);
    }
    uint4 hB;
    #pragma unroll
    for (int t1 = 0; t1 < 2; ++t1) {
        bf16x8 Aw = {0, 0, 0, 0, 0, 0, 0, 0};  // A[j'=arow][i] = W1 row
        if (kgrp < 2) {
            const float4* wp = (const float4*)(W1 + (t1 * 16 + arow) * 16 + kgrp * 8);
            float4 a = wp[0], bb2 = wp[1];
            Aw[0] = f2bf(a.x);   Aw[1] = f2bf(a.y);   Aw[2] = f2bf(a.z);   Aw[3] = f2bf(a.w);
            Aw[4] = f2bf(bb2.x); Aw[5] = f2bf(bb2.y); Aw[6] = f2bf(bb2.z); Aw[7] = f2bf(bb2.w);
        }
        float4 cb = *(const float4*)(b1 + t1 * 16 + kgrp * 4);
        f32x4 c0 = {cb.x, cb.y, cb.z, cb.w};
        f32x4 hr = __builtin_amdgcn_mfma_f32_16x16x32_bf16(Aw, Bm, c0, 0, 0, 0);
        // lane holds h[j'=16t1+4kgrp+q][m=arow own] -> pi-slot order
        unsigned w0 = pk(silu(hr[0]), silu(hr[1]));
        unsigned w1 = pk(silu(hr[2]), silu(hr[3]));
        if (t1 == 0) { hB.x = w0; hB.y = w1; } else { hB.z = w0; hB.w = w1; }
    }
    const bf16x8 B8h = *(bf16x8*)&hB;

    __syncthreads();   // the ONLY barrier: w2t/b2c staged

    // ---- layer 2: 9 swapped MFMAs; C carries compact b2 per (rc) ----
    f32x4 acc[9];
    #pragma unroll
    for (int t = 0; t < 9; ++t) {
        bf16x8 a2 = *(const bf16x8*)(w2t + ((t * 4 + kgrp) * 16 + arow) * 8);
        f32x4 c0 = *(const f32x4*)(b2c + t * 16 + kgrp * 4);  // b2c[16t+4kgrp+q]
        acc[t] = __builtin_amdgcn_mfma_f32_16x16x32_bf16(a2, B8h, c0, 0, 0, 0);
    }

    // ---- register epilogue: z-scatter into y[16], static per kgrp ----
    float y[16];
    #pragma unroll
    for (int k = 0; k < 16; ++k) y[k] = 0.0f;
    switch (kgrp) {
        case 0:  epi<0>(acc, dxv, y); break;
        case 1:  epi<1>(acc, dxv, y); break;
        case 2:  epi<2>(acc, dxv, y); break;
        default: epi<3>(acc, dxv, y); break;
    }

    // ---- y_k = sum over 4 kgrp-lanes: butterfly over lanes 16, 32 ----
    #pragma unroll
    for (int k = 0; k < 16; ++k)
        y[k] += __shfl_xor(y[k], 16, 64);
    #pragma unroll
    for (int k = 0; k < 16; ++k)
        y[k] += __shfl_xor(y[k], 32, 64);

    float d = 0.0f;
    #pragma unroll
    for (int k = 0; k < 16; ++k)
        d = fmaf(y[k], y[k], d);

    if (kgrp == 0)
        out[bn * 256 + mc * 64 + wid * 16 + arow] = __fsqrt_rn(fmaxf(d, 1e-6f));
}

extern "C" void kernel_launch(void* const* d_in, const int* in_sizes, int n_in,
                              void* d_out, int out_size, void* d_ws, size_t ws_size,
                              hipStream_t stream) {
    const float* x1 = (const float*)d_in[0];
    const float* x2 = (const float*)d_in[1];
    const float* W1 = (const float*)d_in[2];
    const float* b1 = (const float*)d_in[3];
    const float* W2 = (const float*)d_in[4];
    const float* b2 = (const float*)d_in[5];
    float* out = (float*)d_out;

    rm_kernel<<<2048, 256, 0, stream>>>(x1, x2, W1, b1, W2, b2, out);
}